// Round 1
// baseline (1142.814 us; speedup 1.0000x reference)
//
#include <hip/hip_runtime.h>
#include <cstdint>
#include <cstddef>

#define NNODES 502
#define NKG    500
#define NEDGE  4000
#define NET    4502   // NEDGE + NNODES self loops
#define BB     128
#define DD     1024
#define HH     256
#define MROWS  (BB*NNODES)   // 64256

// ---------------- edge helpers ----------------
// i64mode: buffer is int64; low words at even int32 positions.
__device__ inline void get_edge(const int* __restrict__ e, int i, int i64mode,
                                int& src, int& dst) {
  if (i < NEDGE) {
    if (i64mode) { src = e[2*i]; dst = e[2*NEDGE + 2*i]; }
    else         { src = e[i];   dst = e[NEDGE + i]; }
  } else {
    src = dst = i - NEDGE;   // self loop
  }
  src = min(max(src, 0), NNODES-1);
  dst = min(max(dst, 0), NNODES-1);
}

__global__ void detect_kernel(const int* __restrict__ e, int* __restrict__ flag) {
  // If any odd int32 word among the first 256 pairs is nonzero -> int32 layout.
  int v = e[2*threadIdx.x + 1];
  if (v != 0) atomicOr(flag, 1);
}

__global__ void deg_kernel(const int* __restrict__ e, const int* __restrict__ flag,
                           int* __restrict__ deg) {
  int i = blockIdx.x*256 + threadIdx.x;
  if (i >= NET) return;
  int src, dst; get_edge(e, i, *flag == 0, src, dst);
  atomicAdd(&deg[dst], 1);
}

__global__ void scan_kernel(const int* __restrict__ deg, float* __restrict__ dinv,
                            int* __restrict__ rp, int* __restrict__ cursor) {
  __shared__ int s[512];
  int t = threadIdx.x;
  int cnt = (t < NNODES) ? deg[t] : 0;
  s[t] = cnt;
  if (t < NNODES) dinv[t] = rsqrtf((float)cnt);  // deg>=1 (self loops)
  __syncthreads();
  for (int off = 1; off < 512; off <<= 1) {
    int v = (t >= off) ? s[t-off] : 0;
    __syncthreads();
    s[t] += v;
    __syncthreads();
  }
  if (t == 0) rp[0] = 0;
  if (t < NNODES) { rp[t+1] = s[t]; cursor[t] = s[t] - cnt; }
}

__global__ void fill_kernel(const int* __restrict__ e, const int* __restrict__ flag,
                            const float* __restrict__ dinv, int* __restrict__ cursor,
                            int* __restrict__ colA, float* __restrict__ valA) {
  int i = blockIdx.x*256 + threadIdx.x;
  if (i >= NET) return;
  int src, dst; get_edge(e, i, *flag == 0, src, dst);
  int pos = atomicAdd(&cursor[dst], 1);
  colA[pos] = src;
  valA[pos] = dinv[src] * dinv[dst];
}

// ---------------- layer-1 GEMM: [628,1024] @ [1024,256] ----------------
__global__ __launch_bounds__(256) void gemm1_kernel(
    const float* __restrict__ base, const float* __restrict__ sensor,
    const float* __restrict__ W1, float* __restrict__ hcat) {
  __shared__ float arow[8][DD];   // 32 KB
  int tid = threadIdx.x;
  int r0 = blockIdx.x * 8;
  for (int j = tid; j < 8*DD; j += 256) {
    int r = r0 + (j >> 10), c = j & (DD-1);
    float v = 0.f;
    if (r < NKG) v = base[r*DD + c];
    else if (r < NKG+BB) v = sensor[(r-NKG)*DD + c];
    arow[j >> 10][c] = v;
  }
  __syncthreads();
  float acc[8] = {0,0,0,0,0,0,0,0};
  for (int k = 0; k < DD; k += 4) {
    float w0 = W1[(k+0)*HH + tid];
    float w1 = W1[(k+1)*HH + tid];
    float w2 = W1[(k+2)*HH + tid];
    float w3 = W1[(k+3)*HH + tid];
#pragma unroll
    for (int i = 0; i < 8; ++i) {
      float4 a = *(const float4*)&arow[i][k];
      acc[i] += a.x*w0 + a.y*w1 + a.z*w2 + a.w*w3;
    }
  }
#pragma unroll
  for (int i = 0; i < 8; ++i) {
    int r = r0 + i;
    if (r < NKG+BB) hcat[r*HH + tid] = acc[i];
  }
}

// ---------------- layer-1 aggregation decomposition ----------------
// A[n,h] = sum_{in-edges, src<500} norm*h_shared[src,h];  c[n] = sum_{src==500} norm
__global__ void ac_kernel(const int* __restrict__ rp, const int* __restrict__ colA,
                          const float* __restrict__ valA, const float* __restrict__ hcat,
                          float* __restrict__ Abuf, float* __restrict__ cbuf) {
  int n = blockIdx.x, h = threadIdx.x;
  int s = rp[n], e = rp[n+1];
  float acc = 0.f, cacc = 0.f;
  for (int t = s; t < e; ++t) {
    int cl = colA[t]; float v = valA[t];
    if (cl < NKG) acc += v * hcat[cl*HH + h];
    else if (cl == NKG) cacc += v;
    // cl == 501 -> zero row, skip
  }
  Abuf[n*HH + h] = acc;
  if (h == 0) cbuf[n] = cacc;
}

// analytic BN1 stats: out1[b,n,h] = A[n,h] + c[n]*s[b,h]
__global__ void bn1_kernel(const float* __restrict__ Abuf, const float* __restrict__ cbuf,
                           const float* __restrict__ hcat, const float* __restrict__ gamma,
                           const float* __restrict__ beta, float* __restrict__ scale,
                           float* __restrict__ shift) {
  int h = threadIdx.x;
  float sA = 0, sAA = 0, sAc = 0, sc = 0, scc = 0;
  for (int n = 0; n < NNODES; ++n) {
    float a = Abuf[n*HH + h]; float cn = cbuf[n];
    sA += a; sAA += a*a; sAc += a*cn; sc += cn; scc += cn*cn;
  }
  float ss = 0, sss = 0;
  for (int b = 0; b < BB; ++b) {
    float v = hcat[(NKG + b)*HH + h]; ss += v; sss += v*v;
  }
  const float cnt = (float)MROWS;
  float mean = ((float)BB * sA + sc*ss) / cnt;
  float msq  = ((float)BB * sAA + 2.f*sAc*ss + scc*sss) / cnt;
  float var  = msq - mean*mean;
  float scl  = gamma[h] * rsqrtf(var + 1e-5f);
  scale[h] = scl; shift[h] = beta[h] - mean*scl;
}

__global__ void x2_kernel(const float* __restrict__ Abuf, const float* __restrict__ cbuf,
                          const float* __restrict__ hcat, const float* __restrict__ scale,
                          const float* __restrict__ shift, float* __restrict__ X) {
  int i = blockIdx.x*256 + threadIdx.x;
  int h = i & 255;
  int bn = i >> 8;
  int b = bn / NNODES;
  int n = bn - b*NNODES;
  float o = Abuf[n*HH + h] + cbuf[n] * hcat[(NKG + b)*HH + h];
  float y = o*scale[h] + shift[h];
  X[i] = (y > 0.f) ? y : expm1f(y);
}

// ---------------- fp32 tiled GEMM: C[M,Nn] = A[M,K] @ B[K,Nn] ----------------
#define GBM 128
#define GBN 128
#define GBK 16
__global__ __launch_bounds__(256) void gemm_f32(const float* __restrict__ A,
                                                const float* __restrict__ Bm,
                                                float* __restrict__ C,
                                                int M, int K, int Nn) {
  __shared__ float As[GBK][GBM];
  __shared__ float Bs[GBK][GBN];
  int tid = threadIdx.x;
  int tx = tid & 15, ty = tid >> 4;
  int row0 = blockIdx.y*GBM, col0 = blockIdx.x*GBN;
  float acc[8][8] = {};
  for (int k0 = 0; k0 < K; k0 += GBK) {
#pragma unroll
    for (int q = 0; q < 2; ++q) {              // A tile: 128x16 = 512 float4
      int f4 = tid + q*256;
      int r = f4 >> 2, kc = (f4 & 3)*4;
      float4 v = make_float4(0.f, 0.f, 0.f, 0.f);
      if (row0 + r < M) v = *(const float4*)&A[(size_t)(row0+r)*K + k0 + kc];
      As[kc+0][r] = v.x; As[kc+1][r] = v.y; As[kc+2][r] = v.z; As[kc+3][r] = v.w;
    }
#pragma unroll
    for (int q = 0; q < 2; ++q) {              // B tile: 16x128 = 512 float4
      int f4 = tid + q*256;
      int kr = f4 >> 5, c4 = (f4 & 31)*4;
      *(float4*)&Bs[kr][c4] = *(const float4*)&Bm[(size_t)(k0+kr)*Nn + col0 + c4];
    }
    __syncthreads();
#pragma unroll
    for (int kk = 0; kk < GBK; ++kk) {
      float4 a0 = *(const float4*)&As[kk][ty*8];
      float4 a1 = *(const float4*)&As[kk][ty*8 + 4];
      float4 b0 = *(const float4*)&Bs[kk][tx*8];
      float4 b1 = *(const float4*)&Bs[kk][tx*8 + 4];
      float av[8] = {a0.x,a0.y,a0.z,a0.w,a1.x,a1.y,a1.z,a1.w};
      float bv[8] = {b0.x,b0.y,b0.z,b0.w,b1.x,b1.y,b1.z,b1.w};
#pragma unroll
      for (int i = 0; i < 8; ++i)
#pragma unroll
        for (int j = 0; j < 8; ++j)
          acc[i][j] += av[i]*bv[j];
    }
    __syncthreads();
  }
#pragma unroll
  for (int i = 0; i < 8; ++i) {
    int r = row0 + ty*8 + i;
    if (r < M) {
      float4 o0 = make_float4(acc[i][0], acc[i][1], acc[i][2], acc[i][3]);
      float4 o1 = make_float4(acc[i][4], acc[i][5], acc[i][6], acc[i][7]);
      *(float4*)&C[(size_t)r*Nn + col0 + tx*8]     = o0;
      *(float4*)&C[(size_t)r*Nn + col0 + tx*8 + 4] = o1;
    }
  }
}

// ---------------- aggregation (layers 2/3), in place, + BN stat partials ----------------
// grid (4 channel-groups of 64, 128 batches); LDS-staged per-batch slice
__global__ __launch_bounds__(256) void agg_kernel(float* __restrict__ buf,
    const int* __restrict__ rp, const int* __restrict__ colA,
    const float* __restrict__ valA, float* __restrict__ sums, float* __restrict__ ssqs) {
  extern __shared__ float tile[];            // 502*64 floats + 256 red
  float* red = tile + NNODES*64;
  int cg = blockIdx.x, b = blockIdx.y;
  int tid = threadIdx.x;
  const float* src = buf + ((size_t)b*NNODES)*HH + cg*64;
  for (int j = tid; j < NNODES*64; j += 256) {
    int n = j >> 6, h = j & 63;
    tile[j] = src[n*HH + h];
  }
  __syncthreads();
  int h = tid & 63, n0 = tid >> 6;
  float lsum = 0.f, lsq = 0.f;
  for (int n = n0; n < NNODES; n += 4) {
    int s = rp[n], e = rp[n+1];
    float acc = 0.f;
    for (int t = s; t < e; ++t) acc += valA[t] * tile[colA[t]*64 + h];
    buf[((size_t)b*NNODES + n)*HH + cg*64 + h] = acc;
    lsum += acc; lsq += acc*acc;
  }
  __syncthreads();
  red[tid] = lsum; __syncthreads();
  if (tid < 64) {
    float t = red[tid] + red[tid+64] + red[tid+128] + red[tid+192];
    atomicAdd(&sums[cg*64 + tid], t);
  }
  __syncthreads();
  red[tid] = lsq; __syncthreads();
  if (tid < 64) {
    float t = red[tid] + red[tid+64] + red[tid+128] + red[tid+192];
    atomicAdd(&ssqs[cg*64 + tid], t);
  }
}

__global__ void finalize_kernel(const float* __restrict__ sums, const float* __restrict__ ssqs,
                                const float* __restrict__ gamma, const float* __restrict__ beta,
                                float* __restrict__ scale, float* __restrict__ shift) {
  int h = threadIdx.x;
  const float cnt = (float)MROWS;
  float mean = sums[h] / cnt;
  float var  = ssqs[h] / cnt - mean*mean;
  float scl  = gamma[h] * rsqrtf(var + 1e-5f);
  scale[h] = scl; shift[h] = beta[h] - mean*scl;
}

__global__ void bnelu_inplace_kernel(float* __restrict__ buf, const float* __restrict__ scale,
                                     const float* __restrict__ shift) {
  int i = blockIdx.x*256 + threadIdx.x;
  int h = i & 255;
  float y = buf[i]*scale[h] + shift[h];
  buf[i] = (y > 0.f) ? y : expm1f(y);
}

__global__ void bnelu_out_kernel(float* __restrict__ dst, const float* __restrict__ srcb,
                                 const float* __restrict__ scale, const float* __restrict__ shift) {
  int i = blockIdx.x*256 + threadIdx.x;
  int h = i & 255;
  float y = srcb[i]*scale[h] + shift[h];
  dst[i] = (y > 0.f) ? y : expm1f(y);
}

extern "C" void kernel_launch(void* const* d_in, const int* in_sizes, int n_in,
                              void* d_out, int out_size, void* d_ws, size_t ws_size,
                              hipStream_t stream) {
  const float* sensor = (const float*)d_in[0];
  const float* base   = (const float*)d_in[1];
  const int*   eidx   = (const int*)d_in[2];
  const float* W1 = (const float*)d_in[3];
  const float* g1 = (const float*)d_in[5];
  const float* be1= (const float*)d_in[6];
  const float* W2 = (const float*)d_in[7];
  const float* g2 = (const float*)d_in[9];
  const float* be2= (const float*)d_in[10];
  const float* W3 = (const float*)d_in[11];
  const float* g3 = (const float*)d_in[13];
  const float* be3= (const float*)d_in[14];

  char* ws = (char*)d_ws;
  int*   deg    = (int*)(ws + 0);          // [zeroed]
  float* sum2   = (float*)(ws + 2048);     // [zeroed]
  float* ssq2   = (float*)(ws + 3072);     // [zeroed]
  float* sum3   = (float*)(ws + 4096);     // [zeroed]
  float* ssq3   = (float*)(ws + 5120);     // [zeroed]
  float* cbuf   = (float*)(ws + 6144);
  int*   cursor = (int*)(ws + 8192);
  int*   flag   = (int*)(ws + 10240);      // [zeroed]
  float* dinv   = (float*)(ws + 12288);
  int*   rp     = (int*)(ws + 14336);
  int*   colA   = (int*)(ws + 16384);
  float* valA   = (float*)(ws + 34816);
  float* scale1 = (float*)(ws + 53248);
  float* shift1 = (float*)(ws + 54272);
  float* scale2 = (float*)(ws + 55296);
  float* shift2 = (float*)(ws + 56320);
  float* scale3 = (float*)(ws + 57344);
  float* shift3 = (float*)(ws + 58368);
  float* Abuf   = (float*)(ws + 61440);                 // 502*256 f
  float* hcat   = (float*)(ws + 61440 + 514048 + 2048); // 628*256 f
  float* X      = (float*)(ws + 61440 + 514048 + 2048 + 643072 + 1024); // 64256*256 f
  float* out    = (float*)d_out;

  hipMemsetAsync(ws, 0, 12288, stream);
  detect_kernel<<<1, 256, 0, stream>>>(eidx, flag);
  deg_kernel<<<(NET+255)/256, 256, 0, stream>>>(eidx, flag, deg);
  scan_kernel<<<1, 512, 0, stream>>>(deg, dinv, rp, cursor);
  fill_kernel<<<(NET+255)/256, 256, 0, stream>>>(eidx, flag, dinv, cursor, colA, valA);
  gemm1_kernel<<<(NKG+BB+7)/8, 256, 0, stream>>>(base, sensor, W1, hcat);
  ac_kernel<<<NNODES, 256, 0, stream>>>(rp, colA, valA, hcat, Abuf, cbuf);
  bn1_kernel<<<1, 256, 0, stream>>>(Abuf, cbuf, hcat, g1, be1, scale1, shift1);
  x2_kernel<<<MROWS, 256, 0, stream>>>(Abuf, cbuf, hcat, scale1, shift1, X);

  gemm_f32<<<dim3(2, (MROWS+GBM-1)/GBM), 256, 0, stream>>>(X, W2, out, MROWS, HH, HH);
  size_t aggLds = (size_t)(NNODES*64 + 256) * 4;
  agg_kernel<<<dim3(4, BB), 256, aggLds, stream>>>(out, rp, colA, valA, sum2, ssq2);
  finalize_kernel<<<1, 256, 0, stream>>>(sum2, ssq2, g2, be2, scale2, shift2);
  bnelu_inplace_kernel<<<MROWS, 256, 0, stream>>>(out, scale2, shift2);

  gemm_f32<<<dim3(2, (MROWS+GBM-1)/GBM), 256, 0, stream>>>(out, W3, X, MROWS, HH, HH);
  agg_kernel<<<dim3(4, BB), 256, aggLds, stream>>>(X, rp, colA, valA, sum3, ssq3);
  finalize_kernel<<<1, 256, 0, stream>>>(sum3, ssq3, g3, be3, scale3, shift3);
  bnelu_out_kernel<<<MROWS, 256, 0, stream>>>(out, X, scale3, shift3);
}

// Round 2
// 446.232 us; speedup vs baseline: 2.5610x; 2.5610x over previous
//
#include <hip/hip_runtime.h>
#include <cstdint>
#include <cstddef>

#define NNODES 502
#define NKG    500
#define NPAD   512
#define NEDGE  4000
#define NET    4502   // NEDGE + NNODES self loops
#define BB     128
#define DD     1024
#define HH     256
#define MROWS  (BB*NNODES)   // 64256
#define MT     65536         // BB*NPAD padded rows

typedef short short8 __attribute__((ext_vector_type(8)));
typedef float f32x4  __attribute__((ext_vector_type(4)));

__device__ __forceinline__ unsigned short f2bf(float f) {
  union { float f; unsigned int u; } v; v.f = f;
  unsigned int r = v.u + 0x7fffu + ((v.u >> 16) & 1u);
  return (unsigned short)(r >> 16);
}

// async global->LDS, 16B per lane; LDS dest = wave-uniform base + lane*16
__device__ __forceinline__ void stage16(const void* g, void* l) {
  __builtin_amdgcn_global_load_lds((__attribute__((address_space(1))) void*)g,
                                   (__attribute__((address_space(3))) void*)l, 16, 0, 0);
}

// D = A*B + D, 16x16x32 bf16. asm avoids builtin operand-type ambiguity.
__device__ __forceinline__ void mfma16(f32x4& c, short8 a, short8 b) {
  asm volatile("v_mfma_f32_16x16x32_bf16 %0, %1, %2, %0" : "+v"(c) : "v"(a), "v"(b));
}

// ---------------- edge helpers ----------------
__device__ inline void get_edge(const int* __restrict__ e, int i, int i64mode,
                                int& src, int& dst) {
  if (i < NEDGE) {
    if (i64mode) { src = e[2*i]; dst = e[2*NEDGE + 2*i]; }
    else         { src = e[i];   dst = e[NEDGE + i]; }
  } else {
    src = dst = i - NEDGE;   // self loop
  }
  src = min(max(src, 0), NNODES-1);
  dst = min(max(dst, 0), NNODES-1);
}

__global__ void detect_kernel(const int* __restrict__ e, int* __restrict__ flag) {
  int v = e[2*threadIdx.x + 1];
  if (v != 0) atomicOr(flag, 1);
}

__global__ void deg_kernel(const int* __restrict__ e, const int* __restrict__ flag,
                           int* __restrict__ deg) {
  int i = blockIdx.x*256 + threadIdx.x;
  if (i >= NET) return;
  int src, dst; get_edge(e, i, *flag == 0, src, dst);
  atomicAdd(&deg[dst], 1);
}

__global__ void scan_kernel(const int* __restrict__ deg, float* __restrict__ dinv,
                            int* __restrict__ rp, int* __restrict__ cursor) {
  __shared__ int s[512];
  int t = threadIdx.x;
  int cnt = (t < NNODES) ? deg[t] : 0;
  s[t] = cnt;
  if (t < NNODES) dinv[t] = rsqrtf((float)cnt);
  __syncthreads();
  for (int off = 1; off < 512; off <<= 1) {
    int v = (t >= off) ? s[t-off] : 0;
    __syncthreads();
    s[t] += v;
    __syncthreads();
  }
  if (t == 0) rp[0] = 0;
  if (t < NNODES) { rp[t+1] = s[t]; cursor[t] = s[t] - cnt; }
}

__global__ void fill_kernel(const int* __restrict__ e, const int* __restrict__ flag,
                            const float* __restrict__ dinv, int* __restrict__ cursor,
                            int* __restrict__ colA, float* __restrict__ valA) {
  int i = blockIdx.x*256 + threadIdx.x;
  if (i >= NET) return;
  int src, dst; get_edge(e, i, *flag == 0, src, dst);
  int pos = atomicAdd(&cursor[dst], 1);
  colA[pos] = src;
  valA[pos] = dinv[src] * dinv[dst];
}

// dense normalized adjacency (fp32 accumulate in d_out scratch, handles dup edges)
__global__ void sdf_kernel(const int* __restrict__ e, const int* __restrict__ flag,
                           const float* __restrict__ dinv, float* __restrict__ Sdf) {
  int i = blockIdx.x*256 + threadIdx.x;
  if (i >= NET) return;
  int src, dst; get_edge(e, i, *flag == 0, src, dst);
  atomicAdd(&Sdf[dst*NPAD + src], dinv[src]*dinv[dst]);
}

__global__ void sdcvt_kernel(const float* __restrict__ Sdf, unsigned short* __restrict__ Sd) {
  int i = blockIdx.x*256 + threadIdx.x;   // 512*512
  Sd[i] = f2bf(Sdf[i]);
}

// W [256,256] fp32 -> Wt[n][k] bf16 (transposed)
__global__ void wt_kernel(const float* __restrict__ W, unsigned short* __restrict__ Wt) {
  int n = blockIdx.x, k = threadIdx.x;
  Wt[n*HH + k] = f2bf(W[k*HH + n]);
}

// ---------------- layer-1 GEMM: [628,1024] @ [1024,256] fp32 ----------------
__global__ __launch_bounds__(256) void gemm1_kernel(
    const float* __restrict__ base, const float* __restrict__ sensor,
    const float* __restrict__ W1, float* __restrict__ hcat) {
  __shared__ float arow[8][DD];
  int tid = threadIdx.x;
  int r0 = blockIdx.x * 8;
  for (int j = tid; j < 8*DD; j += 256) {
    int r = r0 + (j >> 10), c = j & (DD-1);
    float v = 0.f;
    if (r < NKG) v = base[r*DD + c];
    else if (r < NKG+BB) v = sensor[(r-NKG)*DD + c];
    arow[j >> 10][c] = v;
  }
  __syncthreads();
  float acc[8] = {0,0,0,0,0,0,0,0};
  for (int k = 0; k < DD; k += 4) {
    float w0 = W1[(k+0)*HH + tid];
    float w1 = W1[(k+1)*HH + tid];
    float w2 = W1[(k+2)*HH + tid];
    float w3 = W1[(k+3)*HH + tid];
#pragma unroll
    for (int i = 0; i < 8; ++i) {
      float4 a = *(const float4*)&arow[i][k];
      acc[i] += a.x*w0 + a.y*w1 + a.z*w2 + a.w*w3;
    }
  }
#pragma unroll
  for (int i = 0; i < 8; ++i) {
    int r = r0 + i;
    if (r < NKG+BB) hcat[r*HH + tid] = acc[i];
  }
}

// layer-1 decomposition: A[n,h] over shared srcs, c[n] = coeff of sensor row
__global__ void ac_kernel(const int* __restrict__ rp, const int* __restrict__ colA,
                          const float* __restrict__ valA, const float* __restrict__ hcat,
                          float* __restrict__ Abuf, float* __restrict__ cbuf) {
  int n = blockIdx.x, h = threadIdx.x;
  int s = rp[n], e = rp[n+1];
  float acc = 0.f, cacc = 0.f;
  for (int t = s; t < e; ++t) {
    int cl = colA[t]; float v = valA[t];
    if (cl < NKG) acc += v * hcat[cl*HH + h];
    else if (cl == NKG) cacc += v;
  }
  Abuf[n*HH + h] = acc;
  if (h == 0) cbuf[n] = cacc;
}

__global__ void bn1_kernel(const float* __restrict__ Abuf, const float* __restrict__ cbuf,
                           const float* __restrict__ hcat, const float* __restrict__ gamma,
                           const float* __restrict__ beta, float* __restrict__ scale,
                           float* __restrict__ shift) {
  int h = threadIdx.x;
  float sA = 0, sAA = 0, sAc = 0, sc = 0, scc = 0;
  for (int n = 0; n < NNODES; ++n) {
    float a = Abuf[n*HH + h]; float cn = cbuf[n];
    sA += a; sAA += a*a; sAc += a*cn; sc += cn; scc += cn*cn;
  }
  float ss = 0, sss = 0;
  for (int b = 0; b < BB; ++b) {
    float v = hcat[(NKG + b)*HH + h]; ss += v; sss += v*v;
  }
  const float cnt = (float)MROWS;
  float mean = ((float)BB * sA + sc*ss) / cnt;
  float msq  = ((float)BB * sAA + 2.f*sAc*ss + scc*sss) / cnt;
  float var  = msq - mean*mean;
  float scl  = gamma[h] * rsqrtf(var + 1e-5f);
  scale[h] = scl; shift[h] = beta[h] - mean*scl;
}

// layer-1 output -> padded bf16 Xb [MT,256]
__global__ void x2_kernel(const float* __restrict__ Abuf, const float* __restrict__ cbuf,
                          const float* __restrict__ hcat, const float* __restrict__ scale,
                          const float* __restrict__ shift, unsigned short* __restrict__ Xb) {
  int row = blockIdx.x;          // 0..MT-1
  int h = threadIdx.x;
  int b = row >> 9, n = row & (NPAD-1);
  unsigned short out = 0;
  if (n < NNODES) {
    float o = Abuf[n*HH + h] + cbuf[n] * hcat[(NKG + b)*HH + h];
    float y = o*scale[h] + shift[h];
    y = (y > 0.f) ? y : expm1f(y);
    out = f2bf(y);
  }
  Xb[(size_t)row*HH + h] = out;
}

// ---------------- MFMA GEMM-T: Tt[n][m] = sum_k Xb[m][k]*Wt[n][k] ----------------
__global__ __launch_bounds__(256) void gemmT_kernel(
    const unsigned short* __restrict__ Ag,   // Xb [MT,256]
    const unsigned short* __restrict__ Bg,   // Wt [256,256] (n-major)
    unsigned short* __restrict__ Tt) {       // [256, MT]
  __shared__ unsigned short As[128*32];
  __shared__ unsigned short Bs[128*32];
  int tid = threadIdx.x;
  int wave = tid >> 6, lane = tid & 63;
  int l15 = lane & 15, quad = lane >> 4;
  int wm = (wave & 1) * 64, wn = (wave >> 1) * 64;
  int row0 = blockIdx.y * 128, col0 = blockIdx.x * 128;
  f32x4 acc[4][4] = {};
  for (int k0 = 0; k0 < HH; k0 += 32) {
#pragma unroll
    for (int q = 0; q < 2; ++q) {
      int c = wave*128 + q*64 + lane;
      stage16(Ag + (size_t)(row0 + (c>>2))*HH + k0 + (c&3)*8, As + c*8);
      stage16(Bg + (size_t)(col0 + (c>>2))*HH + k0 + (c&3)*8, Bs + c*8);
    }
    __syncthreads();
    short8 af[4], bfv[4];
#pragma unroll
    for (int i = 0; i < 4; ++i) {
      af[i]  = *(const short8*)(As + (wm + i*16 + l15)*32 + quad*8);
      bfv[i] = *(const short8*)(Bs + (wn + i*16 + l15)*32 + quad*8);
    }
#pragma unroll
    for (int mi = 0; mi < 4; ++mi)
#pragma unroll
      for (int ni = 0; ni < 4; ++ni)
        mfma16(acc[mi][ni], af[mi], bfv[ni]);
    __syncthreads();
  }
  asm volatile("s_nop 7\n\ts_nop 7" ::);
#pragma unroll
  for (int ni = 0; ni < 4; ++ni) {
    int n = col0 + wn + ni*16 + l15;
#pragma unroll
    for (int mi = 0; mi < 4; ++mi) {
      int m = row0 + wm + mi*16 + quad*4;
      union { unsigned short u[4]; uint2 v; } p;
#pragma unroll
      for (int r = 0; r < 4; ++r) p.u[r] = f2bf(acc[mi][ni][r]);
      *(uint2*)(Tt + (size_t)n*MT + m) = p.v;
    }
  }
}

// ---------------- MFMA GEMM-S: O_b[node][n] = sum_k Sd[node][k]*Tt[n][b*512+k] ----
__global__ __launch_bounds__(256) void gemmS_kernel(
    const unsigned short* __restrict__ Sd,   // [512,512]
    const unsigned short* __restrict__ Tt,   // [256, MT]
    float* __restrict__ O,                   // d_out [B,502,256]
    float* __restrict__ sums, float* __restrict__ ssqs) {
  __shared__ unsigned short As[128*32];
  __shared__ unsigned short Bs[128*32];
  int tid = threadIdx.x;
  int wave = tid >> 6, lane = tid & 63;
  int l15 = lane & 15, quad = lane >> 4;
  int wm = (wave & 1) * 64, wn = (wave >> 1) * 64;
  int row0 = blockIdx.y * 128, col0 = blockIdx.x * 128;
  int b = blockIdx.z;
  f32x4 acc[4][4] = {};
  for (int k0 = 0; k0 < NPAD; k0 += 32) {
#pragma unroll
    for (int q = 0; q < 2; ++q) {
      int c = wave*128 + q*64 + lane;
      stage16(Sd + (size_t)(row0 + (c>>2))*NPAD + k0 + (c&3)*8, As + c*8);
      stage16(Tt + (size_t)(col0 + (c>>2))*MT + b*NPAD + k0 + (c&3)*8, Bs + c*8);
    }
    __syncthreads();
    short8 af[4], bfv[4];
#pragma unroll
    for (int i = 0; i < 4; ++i) {
      af[i]  = *(const short8*)(As + (wm + i*16 + l15)*32 + quad*8);
      bfv[i] = *(const short8*)(Bs + (wn + i*16 + l15)*32 + quad*8);
    }
#pragma unroll
    for (int mi = 0; mi < 4; ++mi)
#pragma unroll
      for (int ni = 0; ni < 4; ++ni)
        mfma16(acc[mi][ni], af[mi], bfv[ni]);
    __syncthreads();
  }
  asm volatile("s_nop 7\n\ts_nop 7" ::);
  float* Ob = O + (size_t)b*NNODES*HH;
  float ps[4] = {0,0,0,0}, pq[4] = {0,0,0,0};
#pragma unroll
  for (int ni = 0; ni < 4; ++ni) {
    int n = col0 + wn + ni*16 + l15;
#pragma unroll
    for (int mi = 0; mi < 4; ++mi) {
      int node = row0 + wm + mi*16 + quad*4;
#pragma unroll
      for (int r = 0; r < 4; ++r) {
        float v = acc[mi][ni][r];
        if (node + r < NNODES) Ob[(size_t)(node+r)*HH + n] = v;
        ps[ni] += v; pq[ni] += v*v;   // pad rows are exactly 0
      }
    }
  }
  __syncthreads();
  float* red = (float*)As;    // 256 floats
  red[tid] = 0.f;
  __syncthreads();
#pragma unroll
  for (int ni = 0; ni < 4; ++ni) {
    int cl = wn + ni*16 + l15;
    atomicAdd(&red[cl], ps[ni]);
    atomicAdd(&red[128+cl], pq[ni]);
  }
  __syncthreads();
  if (tid < 128) atomicAdd(&sums[col0+tid], red[tid]);
  else atomicAdd(&ssqs[col0+tid-128], red[tid]);
}

__global__ void finalize_kernel(const float* __restrict__ sums, const float* __restrict__ ssqs,
                                const float* __restrict__ gamma, const float* __restrict__ beta,
                                float* __restrict__ scale, float* __restrict__ shift) {
  int h = threadIdx.x;
  const float cnt = (float)MROWS;
  float mean = sums[h] / cnt;
  float var  = ssqs[h] / cnt - mean*mean;
  float scl  = gamma[h] * rsqrtf(var + 1e-5f);
  scale[h] = scl; shift[h] = beta[h] - mean*scl;
}

// BN+ELU, O fp32 -> Xb bf16 padded
__global__ void bnxb_kernel(const float* __restrict__ O, const float* __restrict__ scale,
                            const float* __restrict__ shift, unsigned short* __restrict__ Xb) {
  int idx = blockIdx.x*256 + threadIdx.x;      // over MT*128
  int row = idx >> 7, h2 = (idx & 127)*2;
  int b = row >> 9, n = row & (NPAD-1);
  unsigned int out = 0;
  if (n < NNODES) {
    const float* p = O + ((size_t)(b*NNODES + n)*HH + h2);
    float y0 = p[0]*scale[h2]   + shift[h2];
    float y1 = p[1]*scale[h2+1] + shift[h2+1];
    y0 = (y0 > 0.f) ? y0 : expm1f(y0);
    y1 = (y1 > 0.f) ? y1 : expm1f(y1);
    out = (unsigned int)f2bf(y0) | ((unsigned int)f2bf(y1) << 16);
  }
  *(unsigned int*)(Xb + (size_t)row*HH + h2) = out;
}

// final BN+ELU in place on d_out fp32
__global__ void bnout_kernel(float* __restrict__ O, const float* __restrict__ scale,
                             const float* __restrict__ shift) {
  int i = blockIdx.x*256 + threadIdx.x;   // over MROWS*64
  int h0 = (i & 63)*4;
  float4 v = *(float4*)(O + (size_t)i*4);
  float y0 = v.x*scale[h0]   + shift[h0];
  float y1 = v.y*scale[h0+1] + shift[h0+1];
  float y2 = v.z*scale[h0+2] + shift[h0+2];
  float y3 = v.w*scale[h0+3] + shift[h0+3];
  v.x = (y0 > 0.f) ? y0 : expm1f(y0);
  v.y = (y1 > 0.f) ? y1 : expm1f(y1);
  v.z = (y2 > 0.f) ? y2 : expm1f(y2);
  v.w = (y3 > 0.f) ? y3 : expm1f(y3);
  *(float4*)(O + (size_t)i*4) = v;
}

extern "C" void kernel_launch(void* const* d_in, const int* in_sizes, int n_in,
                              void* d_out, int out_size, void* d_ws, size_t ws_size,
                              hipStream_t stream) {
  const float* sensor = (const float*)d_in[0];
  const float* base   = (const float*)d_in[1];
  const int*   eidx   = (const int*)d_in[2];
  const float* W1 = (const float*)d_in[3];
  const float* g1 = (const float*)d_in[5];
  const float* be1= (const float*)d_in[6];
  const float* W2 = (const float*)d_in[7];
  const float* g2 = (const float*)d_in[9];
  const float* be2= (const float*)d_in[10];
  const float* W3 = (const float*)d_in[11];
  const float* g3 = (const float*)d_in[13];
  const float* be3= (const float*)d_in[14];

  char* ws = (char*)d_ws;
  int*   deg    = (int*)(ws + 0);          // zeroed
  float* sum2   = (float*)(ws + 2048);     // zeroed
  float* ssq2   = (float*)(ws + 3072);     // zeroed
  float* sum3   = (float*)(ws + 4096);     // zeroed
  float* ssq3   = (float*)(ws + 5120);     // zeroed
  float* cbuf   = (float*)(ws + 6144);
  int*   cursor = (int*)(ws + 8192);
  int*   flag   = (int*)(ws + 10240);      // zeroed
  float* dinv   = (float*)(ws + 12288);
  int*   rp     = (int*)(ws + 14336);
  int*   colA   = (int*)(ws + 16384);
  float* valA   = (float*)(ws + 36864);
  float* scale1 = (float*)(ws + 57344);
  float* shift1 = (float*)(ws + 58368);
  float* scale2 = (float*)(ws + 59392);
  float* shift2 = (float*)(ws + 60416);
  float* scale3 = (float*)(ws + 61440);
  float* shift3 = (float*)(ws + 62464);
  float* Abuf   = (float*)(ws + 63488);                  // 502*256 f32
  float* hcat   = (float*)(ws + 577536);                 // 628*256 f32
  unsigned short* Wt2 = (unsigned short*)(ws + 1220608); // 256*256 bf16
  unsigned short* Wt3 = (unsigned short*)(ws + 1351680);
  unsigned short* Sd  = (unsigned short*)(ws + 1482752); // 512*512 bf16
  unsigned short* Xb  = (unsigned short*)(ws + 2007040); // MT*256 bf16
  unsigned short* Tt  = (unsigned short*)(ws + 35561472UL); // 256*MT bf16
  float* out = (float*)d_out;
  float* Sdf = (float*)d_out;   // scratch before layer-2 writes d_out

  hipMemsetAsync(ws, 0, 12288, stream);
  hipMemsetAsync(d_out, 0, NPAD*NPAD*4, stream);
  detect_kernel<<<1, 256, 0, stream>>>(eidx, flag);
  deg_kernel<<<(NET+255)/256, 256, 0, stream>>>(eidx, flag, deg);
  scan_kernel<<<1, 512, 0, stream>>>(deg, dinv, rp, cursor);
  fill_kernel<<<(NET+255)/256, 256, 0, stream>>>(eidx, flag, dinv, cursor, colA, valA);
  sdf_kernel<<<(NET+255)/256, 256, 0, stream>>>(eidx, flag, dinv, Sdf);
  sdcvt_kernel<<<(NPAD*NPAD)/256, 256, 0, stream>>>(Sdf, Sd);
  wt_kernel<<<HH, HH, 0, stream>>>(W2, Wt2);
  wt_kernel<<<HH, HH, 0, stream>>>(W3, Wt3);

  gemm1_kernel<<<(NKG+BB+7)/8, 256, 0, stream>>>(base, sensor, W1, hcat);
  ac_kernel<<<NNODES, 256, 0, stream>>>(rp, colA, valA, hcat, Abuf, cbuf);
  bn1_kernel<<<1, 256, 0, stream>>>(Abuf, cbuf, hcat, g1, be1, scale1, shift1);
  x2_kernel<<<MT, 256, 0, stream>>>(Abuf, cbuf, hcat, scale1, shift1, Xb);

  gemmT_kernel<<<dim3(2, MT/128), 256, 0, stream>>>(Xb, Wt2, Tt);
  gemmS_kernel<<<dim3(2, 4, BB), 256, 0, stream>>>(Sd, Tt, out, sum2, ssq2);
  finalize_kernel<<<1, 256, 0, stream>>>(sum2, ssq2, g2, be2, scale2, shift2);
  bnxb_kernel<<<(MT*128)/256, 256, 0, stream>>>(out, scale2, shift2, Xb);

  gemmT_kernel<<<dim3(2, MT/128), 256, 0, stream>>>(Xb, Wt3, Tt);
  gemmS_kernel<<<dim3(2, 4, BB), 256, 0, stream>>>(Sd, Tt, out, sum3, ssq3);
  finalize_kernel<<<1, 256, 0, stream>>>(sum3, ssq3, g3, be3, scale3, shift3);
  bnout_kernel<<<(MROWS*64)/256, 256, 0, stream>>>(out, scale3, shift3);
}